// Round 3
// baseline (1935137.109 us; speedup 1.0000x reference)
//
#include <hip/hip_runtime.h>

typedef __bf16 bf16x8 __attribute__((ext_vector_type(8)));
typedef float  f32x4  __attribute__((ext_vector_type(4)));
typedef unsigned int u32x4 __attribute__((ext_vector_type(4)));
typedef unsigned short u16;
typedef unsigned int   u32;
typedef unsigned long long u64;

#define NB 128      // batch
#define NT 1024     // time steps
#define NF 128      // input features
#define NH 256      // hidden units (both layers)
#define NG 1024     // 4*NH gate columns
#define M_ROWS (NB*NT)
#define HBPAR (8L*16*NH)   // hbuf parity stride (u16 elements)

__device__ __forceinline__ u16 f2bf(float f) {
  union { float f; u32 u; } c; c.f = f;
  u32 u = c.u;
  return (u16)((u + 0x7fffu + ((u >> 16) & 1u)) >> 16);   // RNE
}

__device__ __forceinline__ float sigm(float x) { return 1.f / (1.f + __expf(-x)); }
__device__ __forceinline__ float tanh_(float x) { return 1.f - 2.f / (1.f + __expf(2.f * x)); }

__device__ __forceinline__ f32x4 mm(bf16x8 a, bf16x8 b, f32x4 c) {
  return __builtin_amdgcn_mfma_f32_16x16x32_bf16(a, b, c, 0, 0, 0);
}

// --- coherent-exchange helpers. SC=true: sc0 (XCD-local L2 coherence point,
// requires the communicating WGs to share an XCD — verified at runtime).
// SC=false: sc1 (device/MALL coherence point, always safe). ---
template<bool SC>
__device__ __forceinline__ u32x4 ld16w(const void* p) {   // load 16B + wait
  u32x4 r;
  if constexpr (SC)
    asm volatile("global_load_dwordx4 %0, %1, off sc0\n\ts_waitcnt vmcnt(0)"
                 : "=v"(r) : "v"(p) : "memory");
  else
    asm volatile("global_load_dwordx4 %0, %1, off sc1\n\ts_waitcnt vmcnt(0)"
                 : "=v"(r) : "v"(p) : "memory");
  return r;
}
template<bool SC>
__device__ __forceinline__ u32x4 ld16(const void* p) {    // load 16B, no wait
  u32x4 r;
  if constexpr (SC)
    asm volatile("global_load_dwordx4 %0, %1, off sc0" : "=v"(r) : "v"(p) : "memory");
  else
    asm volatile("global_load_dwordx4 %0, %1, off sc1" : "=v"(r) : "v"(p) : "memory");
  return r;
}
template<bool SC>
__device__ __forceinline__ void st8(void* p, u64 v) {
  if constexpr (SC)
    asm volatile("global_store_dwordx2 %0, %1, off sc0" :: "v"(p), "v"(v) : "memory");
  else
    asm volatile("global_store_dwordx2 %0, %1, off sc1" :: "v"(p), "v"(v) : "memory");
}
template<bool SC>
__device__ __forceinline__ void st4(void* p, u32 v) {
  if constexpr (SC)
    asm volatile("global_store_dword %0, %1, off sc0" :: "v"(p), "v"(v) : "memory");
  else
    asm volatile("global_store_dword %0, %1, off sc1" :: "v"(p), "v"(v) : "memory");
}
__device__ __forceinline__ void vm0() { asm volatile("s_waitcnt vmcnt(0)" ::: "memory"); }

// ---------------------------------------------------------------------------
// prep: zero tags + handshake metadata (4 KiB region).
// ---------------------------------------------------------------------------
__global__ void prep(u32* __restrict__ flags) {
  int i = blockIdx.x * 256 + threadIdx.x;
  if (i < 1024) flags[i] = 0;
}

// ---------------------------------------------------------------------------
// lstm_scan: one layer, input projection fused. 32 WGs = 8 groups (16 batch
// rows; g = bid&7 -> XCD-aligned under round-robin dispatch) x 4 WGs
// (unit-quarter j = bid>>3). 256 thr = 4 waves; wave w = Keras gate w.
// Resident per wave: U-slice frags (128 VGPR) + W-slice frags (KIN/2 VGPR).
// Per step: acc = bias + x_t@W (before the wait) + h_{t-1}@U; LDS gate
// exchange; pointwise (c fp32 in regs); publish h chunk; tag store.
// Sync: tag-poll protocol, NO atomics / NO acquire-release in the loop.
// sc0 fast path when the group's 4 WGs share an XCD (runtime-verified).
// ---------------------------------------------------------------------------
#define SCAN_BODY(SC0V)                                                         \
  {                                                                             \
    constexpr bool kSC = (SC0V);                                                \
    long budget = 20000000;                                                     \
    bool dead = false;                                                          \
    float cst[4] = {0.f, 0.f, 0.f, 0.f};                                        \
    for (int t = 0; t < NT; ++t) {                                              \
      /* x_t loads + x@W MFMAs: no h dependence, overlaps the wait */           \
      bf16x8 ax[KTIN];                                                          \
      const long xrow = (long)(g * 16 + l15) * NT + t;                          \
      if constexpr (XF32) {                                                     \
        f32x4 xraw[KTIN][2];                                                    \
        _Pragma("unroll")                                                       \
        for (int kt = 0; kt < KTIN; ++kt) {                                     \
          const float* xp = xf + xrow * KIN + kt * 32 + l16 * 8;                \
          xraw[kt][0] = *reinterpret_cast<const f32x4*>(xp);                    \
          xraw[kt][1] = *reinterpret_cast<const f32x4*>(xp + 4);                \
        }                                                                       \
        _Pragma("unroll")                                                       \
        for (int kt = 0; kt < KTIN; ++kt) {                                     \
          union { u16 s[8]; bf16x8 v; } cv;                                     \
          _Pragma("unroll")                                                     \
          for (int e = 0; e < 4; ++e) {                                         \
            cv.s[e] = f2bf(xraw[kt][0][e]); cv.s[4 + e] = f2bf(xraw[kt][1][e]); \
          }                                                                     \
          ax[kt] = cv.v;                                                        \
        }                                                                       \
      } else {                                                                  \
        _Pragma("unroll")                                                       \
        for (int kt = 0; kt < KTIN; ++kt)                                       \
          ax[kt] = *reinterpret_cast<const bf16x8*>(xh + xrow * KIN + kt * 32 + l16 * 8); \
      }                                                                         \
      f32x4 acc[4];                                                             \
      _Pragma("unroll")                                                         \
      for (int nt = 0; nt < 4; ++nt) acc[nt] = f32x4{bb[nt], bb[nt], bb[nt], bb[nt]}; \
      _Pragma("unroll")                                                         \
      for (int kt = 0; kt < KTIN; ++kt)                                         \
        _Pragma("unroll")                                                       \
        for (int nt = 0; nt < 4; ++nt) acc[nt] = mm(ax[kt], wfr[kt][nt], acc[nt]); \
      if (t > 0) {                                                              \
        /* wait for all 4 tags of step t-1 (parity (t-1)&1), all lanes */       \
        const u32 tv = (u32)t;                                                  \
        const u32* rt = tags + (((t + 1) & 1) * 8 + g) * 16;                    \
        if (!dead) {                                                            \
          for (;;) {                                                            \
            u32x4 t4 = ld16w<kSC>(rt);                                          \
            if (t4.x >= tv && t4.y >= tv && t4.z >= tv && t4.w >= tv) break;    \
            __builtin_amdgcn_s_sleep(1);                                        \
            if (--budget <= 0) { dead = true; break; }                          \
          }                                                                     \
        }                                                                       \
        asm volatile("" ::: "memory");                                          \
        /* h_{t-1} A-frags from the coherence point */                          \
        const u16* hb = hbuf + (long)((t + 1) & 1) * HBPAR + (long)g * 4096     \
                      + (long)l15 * NH + l16 * 8;                               \
        u32x4 hv[8];                                                            \
        _Pragma("unroll")                                                       \
        for (int kt = 0; kt < 8; ++kt) hv[kt] = ld16<kSC>(hb + kt * 32);        \
        vm0();                                                                  \
        __builtin_amdgcn_sched_barrier(0);                                      \
        _Pragma("unroll")                                                       \
        for (int kt = 0; kt < 8; ++kt) {                                        \
          union { u32x4 q; bf16x8 v; } cv; cv.q = hv[kt];                       \
          _Pragma("unroll")                                                     \
          for (int nt = 0; nt < 4; ++nt) acc[nt] = mm(cv.v, ufr[kt][nt], acc[nt]); \
        }                                                                       \
      }                                                                         \
      /* gate tiles -> LDS (cross-wave exchange) */                             \
      _Pragma("unroll")                                                         \
      for (int nt = 0; nt < 4; ++nt)                                            \
        _Pragma("unroll")                                                       \
        for (int r = 0; r < 4; ++r)                                             \
          gl[w][l16 * 4 + r][nt * 16 + l15] = acc[nt][r];                       \
      __syncthreads();                                                          \
      f32x4 gi = *reinterpret_cast<const f32x4*>(&gl[0][prow][ublk * 4]);       \
      f32x4 gf = *reinterpret_cast<const f32x4*>(&gl[1][prow][ublk * 4]);       \
      f32x4 gc = *reinterpret_cast<const f32x4*>(&gl[2][prow][ublk * 4]);       \
      f32x4 go = *reinterpret_cast<const f32x4*>(&gl[3][prow][ublk * 4]);       \
      float hh[4];                                                              \
      _Pragma("unroll")                                                         \
      for (int q = 0; q < 4; ++q) {                                             \
        float iv = sigm(gi[q]);                                                 \
        float fv = sigm(gf[q]);                                                 \
        float cd = tanh_(gc[q]);                                                \
        float ov = sigm(go[q]);                                                 \
        cst[q] = fv * cst[q] + iv * cd;                                         \
        hh[q] = ov * tanh_(cst[q]);                                             \
      }                                                                         \
      union { u16 s[4]; u64 q; } hp;                                            \
      _Pragma("unroll")                                                         \
      for (int q = 0; q < 4; ++q) hp.s[q] = f2bf(hh[q]);                        \
      u16* hw = hbuf + (long)(t & 1) * HBPAR + (long)g * 4096                   \
              + (long)prow * NH + ucol;                                         \
      st8<kSC>(hw, hp.q);                                                       \
      if (h_seq)                                                                \
        *reinterpret_cast<u64*>(h_seq + ((long)b * NT + t) * NH + ucol) = hp.q; \
      if (hlast && t == NT - 1)                                                 \
        *reinterpret_cast<f32x4*>(hlast + (long)b * NH + ucol) =                \
            f32x4{hh[0], hh[1], hh[2], hh[3]};                                  \
      vm0();                                                                    \
      __syncthreads();  /* all 256 threads' h stores are at the coh. point */   \
      if (tid == 0) st4<kSC>(tags + ((t & 1) * 8 + g) * 16 + j, (u32)(t + 1));  \
    }                                                                           \
  }

template<int KIN, bool XF32>
__global__ __launch_bounds__(256, 1) void lstm_scan(
    const float* __restrict__ U,     // [NH, NG]
    const float* __restrict__ W,     // [KIN, NG]
    const float* __restrict__ bias,  // [NG]
    const float* __restrict__ xf,    // [NB, NT, KIN] fp32   (XF32)
    const u16*   __restrict__ xh,    // [NB, NT, KIN] bf16   (!XF32)
    u16* __restrict__ hbuf,          // [2][8][16][NH] bf16
    u32* __restrict__ tags,          // [2][8][16] u32 (this layer)
    u32* __restrict__ meta,          // [32] u32 handshake (this layer)
    u32* __restrict__ ready,         // [1] u32 handshake counter
    u16* __restrict__ h_seq,         // [NB*NT, NH] bf16 or null
    float* __restrict__ hlast)       // [NB, NH] f32 or null
{
  const int tid  = threadIdx.x;
  const int lane = tid & 63;
  const int w    = tid >> 6;            // wave index == gate index
  const int g    = blockIdx.x & 7;      // group — XCD-aligned decode
  const int j    = blockIdx.x >> 3;     // unit-quarter: units [64j, 64j+64)
  const int l15  = lane & 15, l16 = lane >> 4;
  constexpr int KTIN = KIN / 32;

  const int colb = w * NH + j * 64;     // gate-column base for this wave

  // Resident W frags (B-operand)
  bf16x8 wfr[KTIN][4];
#pragma unroll
  for (int kt = 0; kt < KTIN; ++kt) {
    const int k0 = kt * 32 + l16 * 8;
#pragma unroll
    for (int nt = 0; nt < 4; ++nt) {
      const float* wp = W + (long)k0 * NG + colb + nt * 16 + l15;
      union { u16 s[8]; bf16x8 v; } cv;
#pragma unroll
      for (int e = 0; e < 8; ++e) cv.s[e] = f2bf(wp[(long)e * NG]);
      wfr[kt][nt] = cv.v;
    }
  }
  // Resident U frags (B-operand), K = NH = 256
  bf16x8 ufr[8][4];
#pragma unroll
  for (int kt = 0; kt < 8; ++kt) {
    const int k0 = kt * 32 + l16 * 8;
#pragma unroll
    for (int nt = 0; nt < 4; ++nt) {
      const float* up = U + (long)k0 * NG + colb + nt * 16 + l15;
      union { u16 s[8]; bf16x8 v; } cv;
#pragma unroll
      for (int e = 0; e < 8; ++e) cv.s[e] = f2bf(up[(long)e * NG]);
      ufr[kt][nt] = cv.v;
    }
  }

  // pointwise mapping: thread -> (batch row, 4 units)
  const int prow = tid & 15;
  const int ublk = tid >> 4;
  const int b    = g * 16 + prow;
  const int ucol = j * 64 + ublk * 4;

  // per-wave bias for acc init (same for all 4 rows of a fragment register)
  float bb[4];
#pragma unroll
  for (int nt = 0; nt < 4; ++nt) bb[nt] = bias[colb + nt * 16 + l15];

  __shared__ __align__(16) float gl[4][16][68];

  // ---- XCD-locality handshake (once; device-scope; bounded) ----
  u32 xcc = 0;
  asm volatile("s_getreg_b32 %0, hwreg(HW_REG_XCC_ID)" : "=s"(xcc));
  if (tid == 0) {
    __hip_atomic_store(meta + blockIdx.x, xcc + 1u, __ATOMIC_RELAXED, __HIP_MEMORY_SCOPE_AGENT);
    __hip_atomic_fetch_add(ready, 1u, __ATOMIC_RELEASE, __HIP_MEMORY_SCOPE_AGENT);
  }
  u32 rv = 0; long itr = 0;
  do {
    rv = __hip_atomic_load(ready, __ATOMIC_ACQUIRE, __HIP_MEMORY_SCOPE_AGENT);
    if (rv >= 32u) break;
    __builtin_amdgcn_s_sleep(2);
  } while (++itr < 10000000L);
  u32 mvAll = __hip_atomic_load(meta + (lane & 31), __ATOMIC_RELAXED, __HIP_MEMORY_SCOPE_AGENT);
  u32 mvGrp = __hip_atomic_load(meta + (g + 8 * (lane & 3)), __ATOMIC_RELAXED, __HIP_MEMORY_SCOPE_AGENT);
  const bool allsame = __all(mvAll == __shfl(mvAll, 0));   // garbage guard
  const bool grpsame = __all(mvGrp == __shfl(mvGrp, 0));   // group co-located
  const bool local = (rv >= 32u) && grpsame && !allsame;

  if (local) SCAN_BODY(true) else SCAN_BODY(false)
}

// ---------------------------------------------------------------------------
// dense head: out[b] = relu(hlast[b,:] . Wd + bd)
// ---------------------------------------------------------------------------
__global__ void dense_out(const float* __restrict__ hl, const float* __restrict__ Wd,
                          const float* __restrict__ bd, float* __restrict__ out) {
  int b = blockIdx.x, l = threadIdx.x;
  f32x4 h  = *reinterpret_cast<const f32x4*>(hl + (long)b * NH + l * 4);
  f32x4 wv = *reinterpret_cast<const f32x4*>(Wd + l * 4);
  float s = h[0] * wv[0] + h[1] * wv[1] + h[2] * wv[2] + h[3] * wv[3];
#pragma unroll
  for (int off = 32; off > 0; off >>= 1) s += __shfl_down(s, off);
  if (l == 0) out[b] = fmaxf(s + bd[0], 0.f);
}

// ---------------------------------------------------------------------------
extern "C" void kernel_launch(void* const* d_in, const int* in_sizes, int n_in,
                              void* d_out, int out_size, void* d_ws, size_t ws_size,
                              hipStream_t stream) {
  const float* x  = (const float*)d_in[0];
  const float* W1 = (const float*)d_in[1];
  const float* U1 = (const float*)d_in[2];
  const float* b1 = (const float*)d_in[3];
  const float* W2 = (const float*)d_in[4];
  const float* U2 = (const float*)d_in[5];
  const float* b2 = (const float*)d_in[6];
  const float* Wd = (const float*)d_in[7];
  const float* bd = (const float*)d_in[8];
  float* out = (float*)d_out;

  char* ws = (char*)d_ws;
  size_t off = 0;
  auto alloc = [&](size_t bytes) -> char* {
    char* p = ws + off;
    off = (off + bytes + 255) & ~(size_t)255;
    return p;
  };
  u16*   h_seq = (u16*)  alloc((size_t)M_ROWS * NH * 2);       // 64 MiB
  u16*   hbuf  = (u16*)  alloc((size_t)2 * HBPAR * 2);         // 128 KiB
  float* hlast = (float*)alloc((size_t)NB * NH * 4);           // 128 KiB
  u32*   flags = (u32*)  alloc(4096);

  if (off > ws_size) {
    // workspace too small: finite sentinel 0x42424242 ~= 48.56 (NOT NaN)
    hipMemsetAsync(d_out, 0x42, (size_t)out_size * sizeof(float), stream);
    return;
  }

  u32* tags1 = flags;        u32* tags2 = flags + 256;
  u32* meta1 = flags + 512;  u32* meta2 = flags + 576;
  u32* rdy1  = flags + 640;  u32* rdy2  = flags + 704;

  prep<<<4, 256, 0, stream>>>(flags);
  lstm_scan<NF, true ><<<32, 256, 0, stream>>>(U1, W1, b1, x, nullptr,
                                               hbuf, tags1, meta1, rdy1, h_seq, nullptr);
  lstm_scan<NH, false><<<32, 256, 0, stream>>>(U2, W2, b2, nullptr, h_seq,
                                               hbuf, tags2, meta2, rdy2, nullptr, hlast);
  dense_out<<<128, 64, 0, stream>>>(hlast, Wd, bd, out);
}

// Round 4
// 5935.588 us; speedup vs baseline: 326.0228x; 326.0228x over previous
//
#include <hip/hip_runtime.h>

typedef __bf16 bf16x8 __attribute__((ext_vector_type(8)));
typedef float  f32x4  __attribute__((ext_vector_type(4)));
typedef unsigned short u16;
typedef unsigned int   u32;
typedef unsigned long long u64;

#define NB 128      // batch
#define NT 1024     // time steps
#define NF 128      // input features
#define NH 256      // hidden units (both layers)
#define NG 1024     // 4*NH gate columns
#define M_ROWS (NB*NT)

__device__ __forceinline__ u16 f2bf(float f) {
  union { float f; u32 u; } c; c.f = f;
  u32 u = c.u;
  return (u16)((u + 0x7fffu + ((u >> 16) & 1u)) >> 16);   // RNE
}

__device__ __forceinline__ float sigm(float x) { return 1.f / (1.f + __expf(-x)); }
__device__ __forceinline__ float tanh_(float x) { return 1.f - 2.f / (1.f + __expf(2.f * x)); }

__device__ __forceinline__ f32x4 mm(bf16x8 a, bf16x8 b, f32x4 c) {
  return __builtin_amdgcn_mfma_f32_16x16x32_bf16(a, b, c, 0, 0, 0);
}

// Relaxed AGENT atomics: coherent at the device coherence point (MALL) by
// SCOPE; no acquire/release cache-maintenance (no buffer_inv / buffer_wbl2).
// Ordering is enforced explicitly: producer = s_waitcnt vmcnt(0) between the
// data stores and the counter add; consumer = control dep + compiler barrier.
__device__ __forceinline__ u64 a_ld64(const u64* p) {
  return __hip_atomic_load((u64*)p, __ATOMIC_RELAXED, __HIP_MEMORY_SCOPE_AGENT);
}
__device__ __forceinline__ void a_st64(u64* p, u64 v) {
  __hip_atomic_store(p, v, __ATOMIC_RELAXED, __HIP_MEMORY_SCOPE_AGENT);
}
__device__ __forceinline__ void vm0() { asm volatile("s_waitcnt vmcnt(0)" ::: "memory"); }

// poll counter until >= target (all 64 lanes, same address -> one coalesced
// request). Returns false if budget exhausted (never hang).
__device__ __forceinline__ bool poll_ge(u32* c, u32 target, long& budget) {
  while (__hip_atomic_load(c, __ATOMIC_RELAXED, __HIP_MEMORY_SCOPE_AGENT) < target) {
    if (--budget <= 0) return false;
  }
  asm volatile("" ::: "memory");   // no data loads hoisted above the poll
  return true;
}

// ---------------------------------------------------------------------------
__global__ void prep(u32* __restrict__ flags) {
  if (blockIdx.x == 0 && threadIdx.x < 256) flags[threadIdx.x] = 0;
}

// ---------------------------------------------------------------------------
// Fused 2-layer LSTM scan. 64 WGs: bid<32 -> layer 1, else layer 2.
// Per layer: 8 groups (16 batch rows) x 4 WGs (unit-quarter). 256 thr =
// 4 waves; wave w = Keras gate w. Resident per wave: U frags (128 VGPR) +
// W frags (KIN/2 VGPR).
// Exchange media (ALL relaxed agent atomics, 8B):
//   L1 recurrence + L1->L2 feed: hseq [NB,NT,NH] bf16 (no parity: one slot
//     per (b,t), written once, read after the gating counter advances).
//   L2 recurrence: h2 [2][8][16][NH] bf16 parity buffer.
// Counters (per group, stride-16 u32): cnt1[g] += 1 per wave per L1 step
// (16/step); cnt2[g] likewise for L2. Gates:
//   L1 step t reads hseq[.,t-1]  after cnt1 >= 16t
//   L2 step t reads hseq[.,t]    after cnt1 >= 16(t+1)   (pipelined feed)
//   L2 step t reads h2 parity    after cnt2 >= 16t
// ---------------------------------------------------------------------------
template<bool L1>
__device__ __forceinline__ void scan(
    const float* __restrict__ U, const float* __restrict__ W,
    const float* __restrict__ bias, const float* __restrict__ xf,
    u64* hseq, u64* h2, u32* cnt1, u32* cnt2, float* hlast,
    int g, int j, float (*gl)[16][68])
{
  const int tid  = threadIdx.x;
  const int lane = tid & 63;
  const int w    = tid >> 6;
  const int l15  = lane & 15, l16 = lane >> 4;
  constexpr int KIN  = L1 ? NF : NH;
  constexpr int KTIN = KIN / 32;

  const int colb = w * NH + j * 64;

  // Resident W frags (B-operand), K = KIN
  bf16x8 wfr[KTIN][4];
#pragma unroll
  for (int kt = 0; kt < KTIN; ++kt) {
    const int k0 = kt * 32 + l16 * 8;
#pragma unroll
    for (int nt = 0; nt < 4; ++nt) {
      const float* wp = W + (long)k0 * NG + colb + nt * 16 + l15;
      union { u16 s[8]; bf16x8 v; } cv;
#pragma unroll
      for (int e = 0; e < 8; ++e) cv.s[e] = f2bf(wp[(long)e * NG]);
      wfr[kt][nt] = cv.v;
    }
  }
  // Resident U frags (B-operand), K = NH
  bf16x8 ufr[8][4];
#pragma unroll
  for (int kt = 0; kt < 8; ++kt) {
    const int k0 = kt * 32 + l16 * 8;
#pragma unroll
    for (int nt = 0; nt < 4; ++nt) {
      const float* up = U + (long)k0 * NG + colb + nt * 16 + l15;
      union { u16 s[8]; bf16x8 v; } cv;
#pragma unroll
      for (int e = 0; e < 8; ++e) cv.s[e] = f2bf(up[(long)e * NG]);
      ufr[kt][nt] = cv.v;
    }
  }

  // pointwise mapping: thread -> (batch row, 4 units)
  const int prow = tid & 15;
  const int ublk = tid >> 4;
  const int b    = g * 16 + prow;
  const int ucol = j * 64 + ublk * 4;

  float bv[4][4];
#pragma unroll
  for (int gg = 0; gg < 4; ++gg)
#pragma unroll
    for (int q = 0; q < 4; ++q) bv[gg][q] = bias[gg * NH + ucol + q];

  u32* c1 = cnt1 + g * 16;
  u32* c2 = cnt2 + g * 16;
  const long abatch = (long)(g * 16 + l15) * NT;   // A-frag batch row base (in rows)

  float cst[4] = {0.f, 0.f, 0.f, 0.f};
  long budget = 20000000;
  bool dead = false;

  for (int t = 0; t < NT; ++t) {
    // ---- input A-frags ----
    bf16x8 ax[KTIN];
    if constexpr (L1) {
      const float* xp0 = xf + (abatch + t) * NF;
      f32x4 xraw[KTIN][2];
#pragma unroll
      for (int kt = 0; kt < KTIN; ++kt) {
        const float* xp = xp0 + kt * 32 + l16 * 8;
        xraw[kt][0] = *reinterpret_cast<const f32x4*>(xp);
        xraw[kt][1] = *reinterpret_cast<const f32x4*>(xp + 4);
      }
#pragma unroll
      for (int kt = 0; kt < KTIN; ++kt) {
        union { u16 s[8]; bf16x8 v; } cv;
#pragma unroll
        for (int e = 0; e < 4; ++e) {
          cv.s[e] = f2bf(xraw[kt][0][e]); cv.s[4 + e] = f2bf(xraw[kt][1][e]);
        }
        ax[kt] = cv.v;
      }
    } else {
      // gate: hseq column t fully published by layer 1
      if (!dead && !poll_ge(c1, 16u * (u32)(t + 1), budget)) dead = true;
      u64* xb = hseq + (abatch + t) * 64;   // 64 u64 per row
#pragma unroll
      for (int kt = 0; kt < KTIN; ++kt) {
        union { u64 q[2]; bf16x8 v; } cv;
        cv.q[0] = a_ld64(xb + kt * 8 + l16 * 2);
        cv.q[1] = a_ld64(xb + kt * 8 + l16 * 2 + 1);
        ax[kt] = cv.v;
      }
    }

    f32x4 acc[4] = {};
#pragma unroll
    for (int kt = 0; kt < KTIN; ++kt)
#pragma unroll
      for (int nt = 0; nt < 4; ++nt) acc[nt] = mm(ax[kt], wfr[kt][nt], acc[nt]);

    // ---- recurrent A-frags ----
    if (t > 0) {
      u32* cr = L1 ? c1 : c2;
      if (!dead && !poll_ge(cr, 16u * (u32)t, budget)) dead = true;
      u64* hb;
      if constexpr (L1) hb = hseq + (abatch + (t - 1)) * 64;
      else              hb = h2 + ((((long)((t + 1) & 1) * 8 + g) * 16) + l15) * 64;
      bf16x8 af[8];
#pragma unroll
      for (int kt = 0; kt < 8; ++kt) {
        union { u64 q[2]; bf16x8 v; } cv;
        cv.q[0] = a_ld64(hb + kt * 8 + l16 * 2);
        cv.q[1] = a_ld64(hb + kt * 8 + l16 * 2 + 1);
        af[kt] = cv.v;
      }
#pragma unroll
      for (int kt = 0; kt < 8; ++kt)
#pragma unroll
        for (int nt = 0; nt < 4; ++nt) acc[nt] = mm(af[kt], ufr[kt][nt], acc[nt]);
    }

    // ---- gate tiles -> LDS (cross-wave exchange) ----
#pragma unroll
    for (int nt = 0; nt < 4; ++nt)
#pragma unroll
      for (int r = 0; r < 4; ++r)
        gl[w][l16 * 4 + r][nt * 16 + l15] = acc[nt][r];
    __syncthreads();

    // ---- pointwise cell update (Keras order i, f, cbar, o) ----
    f32x4 gi = *reinterpret_cast<const f32x4*>(&gl[0][prow][ublk * 4]);
    f32x4 gf = *reinterpret_cast<const f32x4*>(&gl[1][prow][ublk * 4]);
    f32x4 gc = *reinterpret_cast<const f32x4*>(&gl[2][prow][ublk * 4]);
    f32x4 go = *reinterpret_cast<const f32x4*>(&gl[3][prow][ublk * 4]);
    __syncthreads();   // gl reusable next step after this
    float hh[4];
#pragma unroll
    for (int q = 0; q < 4; ++q) {
      float iv = sigm(gi[q] + bv[0][q]);
      float fv = sigm(gf[q] + bv[1][q]);
      float cd = tanh_(gc[q] + bv[2][q]);
      float ov = sigm(go[q] + bv[3][q]);
      cst[q] = fv * cst[q] + iv * cd;
      hh[q] = ov * tanh_(cst[q]);
    }
    union { u16 s[4]; u64 q; } hp;
#pragma unroll
    for (int q = 0; q < 4; ++q) hp.s[q] = f2bf(hh[q]);

    // ---- publish h_t (relaxed atomic -> MALL) ----
    if constexpr (L1) {
      a_st64(hseq + ((long)b * NT + t) * 64 + (ucol >> 2), hp.q);
    } else {
      a_st64(h2 + ((((long)(t & 1) * 8 + g) * 16) + prow) * 64 + (ucol >> 2), hp.q);
      if (t == NT - 1)
        *reinterpret_cast<f32x4*>(hlast + (long)b * NH + ucol) =
            f32x4{hh[0], hh[1], hh[2], hh[3]};
    }

    // completion at coherence point BEFORE counter bump (per-wave bump)
    vm0();
    if (lane == 0)
      __hip_atomic_fetch_add(L1 ? c1 : c2, 1u, __ATOMIC_RELAXED, __HIP_MEMORY_SCOPE_AGENT);
  }
}

__global__ __launch_bounds__(256, 1) void lstm_fused(
    const float* __restrict__ x,
    const float* __restrict__ W1, const float* __restrict__ U1, const float* __restrict__ b1,
    const float* __restrict__ W2, const float* __restrict__ U2, const float* __restrict__ b2,
    u64* hseq, u64* h2, u32* flags, float* hlast)
{
  __shared__ __align__(16) float gl[4][16][68];
  const int bid = blockIdx.x;
  const int sb  = bid & 31;
  u32* cnt1 = flags;         // 8 counters, stride 16
  u32* cnt2 = flags + 128;
  if (bid < 32)
    scan<true >(U1, W1, b1, x, hseq, nullptr, cnt1, cnt2, nullptr, sb & 7, sb >> 3, gl);
  else
    scan<false>(U2, W2, b2, nullptr, hseq, h2, cnt1, cnt2, hlast, sb & 7, sb >> 3, gl);
}

// ---------------------------------------------------------------------------
__global__ void dense_out(const float* __restrict__ hl, const float* __restrict__ Wd,
                          const float* __restrict__ bd, float* __restrict__ out) {
  int b = blockIdx.x, l = threadIdx.x;
  f32x4 h  = *reinterpret_cast<const f32x4*>(hl + (long)b * NH + l * 4);
  f32x4 wv = *reinterpret_cast<const f32x4*>(Wd + l * 4);
  float s = h[0] * wv[0] + h[1] * wv[1] + h[2] * wv[2] + h[3] * wv[3];
#pragma unroll
  for (int off = 32; off > 0; off >>= 1) s += __shfl_down(s, off);
  if (l == 0) out[b] = fmaxf(s + bd[0], 0.f);
}

// ---------------------------------------------------------------------------
extern "C" void kernel_launch(void* const* d_in, const int* in_sizes, int n_in,
                              void* d_out, int out_size, void* d_ws, size_t ws_size,
                              hipStream_t stream) {
  const float* x  = (const float*)d_in[0];
  const float* W1 = (const float*)d_in[1];
  const float* U1 = (const float*)d_in[2];
  const float* b1 = (const float*)d_in[3];
  const float* W2 = (const float*)d_in[4];
  const float* U2 = (const float*)d_in[5];
  const float* b2 = (const float*)d_in[6];
  const float* Wd = (const float*)d_in[7];
  const float* bd = (const float*)d_in[8];
  float* out = (float*)d_out;

  char* ws = (char*)d_ws;
  size_t off = 0;
  auto alloc = [&](size_t bytes) -> char* {
    char* p = ws + off;
    off = (off + bytes + 255) & ~(size_t)255;
    return p;
  };
  u64*   hseq  = (u64*)  alloc((size_t)M_ROWS * NH * 2);       // 64 MiB
  u64*   h2    = (u64*)  alloc((size_t)2 * 8 * 16 * NH * 2);   // 128 KiB
  float* hlast = (float*)alloc((size_t)NB * NH * 4);           // 128 KiB
  u32*   flags = (u32*)  alloc(1024);

  if (off > ws_size) {
    // workspace too small: finite sentinel 0x42424242 ~= 48.56 (NOT NaN)
    hipMemsetAsync(d_out, 0x42, (size_t)out_size * sizeof(float), stream);
    return;
  }

  prep<<<1, 256, 0, stream>>>(flags);
  lstm_fused<<<64, 256, 0, stream>>>(x, W1, U1, b1, W2, U2, b2, hseq, h2, flags, hlast);
  dense_out<<<128, 64, 0, stream>>>(hlast, Wd, bd, out);
}